// Round 11
// baseline (272.502 us; speedup 1.0000x reference)
//
#include <hip/hip_runtime.h>
#include <math.h>

using bf16x8 = __attribute__((ext_vector_type(8))) short;
using f32x4  = __attribute__((ext_vector_type(4))) float;
using u32x2  = __attribute__((ext_vector_type(2))) unsigned int;

namespace {
constexpr int kB  = 4;
constexpr int kLQ = 1024;
constexpr int kLK = 2048;
constexpr int kH  = 1024;
constexpr int kHD = 64;
}

__device__ __forceinline__ unsigned short f2bf(float x) {
  union { float f; unsigned int u; } v; v.f = x;
  unsigned int r = v.u + 0x7fffu + ((v.u >> 16) & 1u);   // RNE
  return (unsigned short)(r >> 16);
}

__device__ __forceinline__ unsigned int pk2(float a, float b) {
  return (unsigned int)f2bf(a) | ((unsigned int)f2bf(b) << 16);
}

__device__ __forceinline__ uint4 pack8(const float4& a, const float4& b) {
  uint4 o;
  o.x = pk2(a.x, a.y); o.y = pk2(a.z, a.w);
  o.z = pk2(b.x, b.y); o.w = pk2(b.z, b.w);
  return o;
}

// async global->LDS 16B copy
typedef const __attribute__((address_space(1))) unsigned int guint_t;
typedef __attribute__((address_space(3))) unsigned int luint_t;
__device__ __forceinline__ void g2l16(const void* g, void* l) {
  __builtin_amdgcn_global_load_lds(
      (guint_t*)g,
      (luint_t*)(unsigned int)(unsigned long long)l,
      16, 0, 0);
}

// --------- prep: 4 weight transposes only (q/k/v cast fused into qkv) -------
__global__ __launch_bounds__(256) void prep_kernel(
    const float* __restrict__ Wq, const float* __restrict__ Wk,
    const float* __restrict__ Wv, const float* __restrict__ Wo,
    unsigned short* __restrict__ WqT, unsigned short* __restrict__ WkT,
    unsigned short* __restrict__ WvT, unsigned short* __restrict__ WoT)
{
  __shared__ float tile[64][65];
  const int t = threadIdx.x;
  int id = blockIdx.x;
  const float* W; unsigned short* Wt; int Kd;
  if (id < 192)      { W = Wq; Wt = WqT; Kd = 768; }
  else if (id < 320) { W = Wk; Wt = WkT; Kd = 512;  id -= 192; }
  else if (id < 448) { W = Wv; Wt = WvT; Kd = 512;  id -= 320; }
  else               { W = Wo; Wt = WoT; Kd = 1024; id -= 448; }
  const int Nd = 1024;
  const int n0 = (id & 15) * 64;
  const int k0 = (id >> 4) * 64;
  const int rr = t >> 4;
  const int c4 = t & 15;
#pragma unroll
  for (int i = 0; i < 4; ++i) {
    const int row = i * 16 + rr;
    const float4 vv = *(const float4*)(W + (size_t)(k0 + row) * Nd + n0 + c4 * 4);
    tile[row][c4*4+0] = vv.x; tile[row][c4*4+1] = vv.y;
    tile[row][c4*4+2] = vv.z; tile[row][c4*4+3] = vv.w;
  }
  __syncthreads();
#pragma unroll
  for (int i = 0; i < 4; ++i) {
    const int n = i * 16 + rr;
    ushort4 o;
    o.x = f2bf(tile[c4*4+0][n]); o.y = f2bf(tile[c4*4+1][n]);
    o.z = f2bf(tile[c4*4+2][n]); o.w = f2bf(tile[c4*4+3][n]);
    *(ushort4*)(Wt + (size_t)(n0 + n) * Kd + k0 + c4 * 4) = o;
  }
}

// ---- GEMM body: 128x128 tile, BK=32, TRIPLE-buffered pipeline --------------
// AFP32=false: R9-proven all-g2l staging, counted `vmcnt(4)` (58.4us qkv).
// AFP32=true : FUSED fp32->bf16 cast in A-staging, per-wave role split:
//   waves 0-1: load A fp32 -> f2bf pack -> ds_write_b128 (T14 async split:
//     regs for tile t+2 issued at iter t; ds_write of tile t+1 during iter t's
//     compute; `lgkmcnt(0)` before each barrier). Two named float4[8] reg sets
//     via 2-unrolled K loop (static indices, no scratch).
//   waves 2-3: g2l16 B with counted `vmcnt(4)` (per-wave vmcnt -> disciplines
//     compose). Same slot/WAR timing as R9: write slot t+1 two barriers after
//     its last read. VGPR ~160 -> 3 waves/SIMD; LDS 48KB -> 3 blocks/CU (= R9).
// Modes 0/1 SWAPPED mfma(B,A): acc reg spans 4 consecutive output cols ->
// float4/ushort4 C-stores. mode 2 unswapped (V-transpose epilogue).
template<bool AFP32>
__device__ __forceinline__ void gemm_body(
    const void* Ain, const unsigned short* __restrict__ Bt,
    const float* __restrict__ bias, void* __restrict__ Cout,
    int N, int K, int bx, int by, int mode, float scale, char* lds)
{
  const int t    = threadIdx.x;
  const int lane = t & 63;
  const int w    = t >> 6;
  const int l15  = lane & 15;
  const int lq8  = (lane >> 4) * 8;
  const int lq4  = (lane >> 4) * 4;
  const int r0   = by * 128;
  const int c0   = bx * 128;
  const int wm   = w >> 1, wn = w & 1;

  f32x4 acc[4][4] = {};

  auto compute = [&](char* buf) {
    bf16x8 af[4], bfr[4];
#pragma unroll
    for (int i = 0; i < 4; ++i) af[i]  = *(const bf16x8*)(buf + (wm*4 + i) * 1024 + lane * 16);
#pragma unroll
    for (int j = 0; j < 4; ++j) bfr[j] = *(const bf16x8*)(buf + 8192 + (wn*4 + j) * 1024 + lane * 16);
#pragma unroll
    for (int i = 0; i < 4; ++i)
#pragma unroll
      for (int j = 0; j < 4; ++j)
        acc[i][j] = (mode == 2)
          ? __builtin_amdgcn_mfma_f32_16x16x32_bf16(af[i], bfr[j], acc[i][j], 0, 0, 0)
          : __builtin_amdgcn_mfma_f32_16x16x32_bf16(bfr[j], af[i], acc[i][j], 0, 0, 0);
  };

  if constexpr (!AFP32) {
    const unsigned short* A = (const unsigned short*)Ain;
    const unsigned short* gsrc[4];
    char* ldst[4];
#pragma unroll
    for (int i = 0; i < 4; ++i) {
      const int g = w * 4 + i;
      const unsigned short* src = (g < 8) ? A : Bt;
      const int rbase = (g < 8) ? (r0 + g * 16) : (c0 + (g - 8) * 16);
      gsrc[i] = src + (size_t)(rbase + l15) * K + lq8;
      ldst[i] = lds + g * 1024 + lane * 16;
    }
#pragma unroll
    for (int i = 0; i < 4; ++i) g2l16(gsrc[i], ldst[i]);
#pragma unroll
    for (int i = 0; i < 4; ++i) g2l16(gsrc[i] + 32, ldst[i] + 16384);
    int slot = 0;
    for (int k0 = 0; k0 < K; k0 += 32) {
      if (k0 + 32 < K) {
        asm volatile("s_waitcnt vmcnt(4)\n\ts_barrier" ::: "memory");
      } else {
        asm volatile("s_waitcnt vmcnt(0)\n\ts_barrier" ::: "memory");
      }
      char* buf = lds + slot * 16384;
      if (k0 + 64 < K) {
        int ns = slot + 2; if (ns >= 3) ns -= 3;
#pragma unroll
        for (int i = 0; i < 4; ++i)
          g2l16(gsrc[i] + k0 + 64, ldst[i] + ns * 16384);
      }
      compute(buf);
      slot = (slot == 2) ? 0 : slot + 1;
    }
  } else {
    const int NT = K / 32;   // even for all K used (16/24/32)
    if (w < 2) {
      // ---- A-cast staging waves (fp32 -> bf16 fused) ----
      const float* fsrc[4];
      char* adst[4];
#pragma unroll
      for (int i = 0; i < 4; ++i) {
        const int g = w * 4 + i;
        fsrc[i] = (const float*)Ain + (size_t)(r0 + g * 16 + l15) * K + lq8;
        adst[i] = lds + g * 1024 + lane * 16;
      }
      float4 sA[8], sB[8];
      // prologue: A(0) -> sA -> slot0; A(1) -> sB
#pragma unroll
      for (int i = 0; i < 4; ++i) {
        sA[2*i]   = *(const float4*)(fsrc[i]);
        sA[2*i+1] = *(const float4*)(fsrc[i] + 4);
      }
#pragma unroll
      for (int i = 0; i < 4; ++i)
        *(uint4*)(adst[i]) = pack8(sA[2*i], sA[2*i+1]);
#pragma unroll
      for (int i = 0; i < 4; ++i) {
        sB[2*i]   = *(const float4*)(fsrc[i] + 32);
        sB[2*i+1] = *(const float4*)(fsrc[i] + 36);
      }
      int slot = 0;
      for (int kt = 0; kt < NT; kt += 2) {
        // --- tile kt: write A(kt+1) from sB, load A(kt+2) -> sA ---
        asm volatile("s_waitcnt lgkmcnt(0)\n\ts_barrier" ::: "memory");
        {
          char* buf = lds + slot * 16384;
          if (kt + 2 < NT) {
#pragma unroll
            for (int i = 0; i < 4; ++i) {
              sA[2*i]   = *(const float4*)(fsrc[i] + (kt + 2) * 32);
              sA[2*i+1] = *(const float4*)(fsrc[i] + (kt + 2) * 32 + 4);
            }
          }
          const int wo = ((slot == 2) ? 0 : slot + 1) * 16384;
#pragma unroll
          for (int i = 0; i < 4; ++i)
            *(uint4*)(adst[i] + wo) = pack8(sB[2*i], sB[2*i+1]);
          compute(buf);
          slot = (slot == 2) ? 0 : slot + 1;
        }
        // --- tile kt+1: write A(kt+2) from sA, load A(kt+3) -> sB ---
        asm volatile("s_waitcnt lgkmcnt(0)\n\ts_barrier" ::: "memory");
        {
          char* buf = lds + slot * 16384;
          if (kt + 3 < NT) {
#pragma unroll
            for (int i = 0; i < 4; ++i) {
              sB[2*i]   = *(const float4*)(fsrc[i] + (kt + 3) * 32);
              sB[2*i+1] = *(const float4*)(fsrc[i] + (kt + 3) * 32 + 4);
            }
          }
          if (kt + 2 < NT) {
            const int wo = ((slot == 2) ? 0 : slot + 1) * 16384;
#pragma unroll
            for (int i = 0; i < 4; ++i)
              *(uint4*)(adst[i] + wo) = pack8(sA[2*i], sA[2*i+1]);
          }
          compute(buf);
          slot = (slot == 2) ? 0 : slot + 1;
        }
      }
    } else {
      // ---- B g2l waves: R9 counted-vmcnt discipline ----
      const unsigned short* gsrc[4];
      char* ldst[4];
#pragma unroll
      for (int i = 0; i < 4; ++i) {
        const int g = (w - 2) * 4 + i;   // B group 0..7
        gsrc[i] = Bt + (size_t)(c0 + g * 16 + l15) * K + lq8;
        ldst[i] = lds + 8192 + g * 1024 + lane * 16;
      }
#pragma unroll
      for (int i = 0; i < 4; ++i) g2l16(gsrc[i], ldst[i]);
#pragma unroll
      for (int i = 0; i < 4; ++i) g2l16(gsrc[i] + 32, ldst[i] + 16384);
      int slot = 0;
      for (int k0 = 0; k0 < K; k0 += 32) {
        if (k0 + 32 < K) {
          asm volatile("s_waitcnt vmcnt(4)\n\ts_barrier" ::: "memory");
        } else {
          asm volatile("s_waitcnt vmcnt(0)\n\ts_barrier" ::: "memory");
        }
        char* buf = lds + slot * 16384;
        if (k0 + 64 < K) {
          int ns = slot + 2; if (ns >= 3) ns -= 3;
#pragma unroll
          for (int i = 0; i < 4; ++i)
            g2l16(gsrc[i] + k0 + 64, ldst[i] + ns * 16384);
        }
        compute(buf);
        slot = (slot == 2) ? 0 : slot + 1;
      }
    }
  }

  if (mode == 2) {
    // unswapped layout: reg spans rows (lq4+r), l15 spans cols
#pragma unroll
    for (int j = 0; j < 4; ++j) {
      const int col = c0 + wn * 64 + j * 16 + l15;
      const float bcol = bias[col];
#pragma unroll
      for (int i = 0; i < 4; ++i) {
        const int row = r0 + wm * 64 + i * 16 + lq4;
        unsigned short* out = (unsigned short*)Cout;
        const int bb = row >> 11;            // kLK = 2048
        const int lk = row & 2047;
        ushort4 o;
        o.x = f2bf(acc[i][j][0] + bcol); o.y = f2bf(acc[i][j][1] + bcol);
        o.z = f2bf(acc[i][j][2] + bcol); o.w = f2bf(acc[i][j][3] + bcol);
        *(ushort4*)(out + (size_t)(bb * kH + col) * kLK + lk) = o;
      }
    }
  } else {
    // swapped layout: l15 spans rows, reg spans 4 consecutive cols
#pragma unroll
    for (int i = 0; i < 4; ++i) {
      const int row = r0 + wm * 64 + i * 16 + l15;
#pragma unroll
      for (int j = 0; j < 4; ++j) {
        const int ncol = c0 + wn * 64 + j * 16 + lq4;
        const float4 b4 = *(const float4*)(bias + ncol);
        if (mode == 0) {
          float4 o;
          o.x = acc[i][j][0] + b4.x; o.y = acc[i][j][1] + b4.y;
          o.z = acc[i][j][2] + b4.z; o.w = acc[i][j][3] + b4.w;
          *(float4*)((float*)Cout + (size_t)row * N + ncol) = o;
        } else {
          ushort4 o;
          o.x = f2bf((acc[i][j][0] + b4.x) * scale);
          o.y = f2bf((acc[i][j][1] + b4.y) * scale);
          o.z = f2bf((acc[i][j][2] + b4.z) * scale);
          o.w = f2bf((acc[i][j][3] + b4.w) * scale);
          *(ushort4*)((unsigned short*)Cout + (size_t)row * N + ncol) = o;
        }
      }
    }
  }
}

// fused Q/K/V projections reading fp32 q/k/v DIRECTLY (cast fused into
// A-staging): blocks 0..255 Q | 256..767 K | 768..1279 V. Unswizzled grid
// (R3 A/B). Q pre-scaled by log2(e)/sqrt(HD).
__global__ __launch_bounds__(256) void qkv_gemm_kernel(
    const float* __restrict__ query, const unsigned short* __restrict__ WqT,
    const float* __restrict__ bq, unsigned short* __restrict__ Qb,
    const float* __restrict__ key, const unsigned short* __restrict__ WkT,
    const float* __restrict__ bk, unsigned short* __restrict__ Kb,
    const float* __restrict__ value, const unsigned short* __restrict__ WvT,
    const float* __restrict__ bv, unsigned short* __restrict__ Vtw)
{
  __shared__ __align__(16) char lds[49152];
  int id = blockIdx.x;
  if (id < 256) {
    gemm_body<true>(query, WqT, bq, Qb, 1024, 768, id & 7, id >> 3, 1,
                    0.18033688011112042f, lds);   // log2(e)/8
  } else if (id < 768) {
    id -= 256;
    gemm_body<true>(key, WkT, bk, Kb, 1024, 512, id & 7, id >> 3, 1, 1.f, lds);
  } else {
    id -= 768;
    gemm_body<true>(value, WvT, bv, Vtw, 1024, 512, id & 7, id >> 3, 2, 1.f, lds);
  }
}

// out projection: fp32 out, 256 blocks (8 x 32 tiles of 128x128), bf16 A path
__global__ __launch_bounds__(256) void out_gemm_kernel(
    const unsigned short* __restrict__ A, const unsigned short* __restrict__ Bt,
    const float* __restrict__ bias, float* __restrict__ C)
{
  __shared__ __align__(16) char lds[49152];
  const int id = blockIdx.x;
  gemm_body<false>(A, Bt, bias, C, 1024, 1024, id & 7, id >> 3, 0, 1.f, lds);
}

// --------------------- MFMA flash attention (bf16, fp32 acc) -----------------
// Q [B*LQ, H] (pre-scaled by log2e/8), K [B*LK, H], Vt [B*H, LK], O [B*LQ, H].
// 8 waves x 16 q-rows (512 threads), kc-tile = 64, DOUBLE-buffered K/V;
// 48KB LDS -> 2 blocks/CU x 8 waves = 16 waves/CU: one wave's quarter-rate
// v_exp_f32 chain overlaps another's MFMA.
// QK^T SWAPPED (mfma(K,Q) = S^T); P 128 rows x 128B XOR-swizzled
// (byte ^= ((5*row)&7)<<4): conflict-free b128 reads, 2-way b64 writes (free).
// PV swapped (mfma(V,P)): lsum lane-local at q=l15, ushort4 O-stores.
__global__ __launch_bounds__(512) void attn_mfma_kernel(
    const unsigned short* __restrict__ Q, const unsigned short* __restrict__ K,
    const unsigned short* __restrict__ Vt, unsigned short* __restrict__ O)
{
  // slot s at s*16384: K tile [0,8K) + V tile [8K,16K). P at 32768 (128 x 128B)
  __shared__ __align__(16) char lds[49152];
  constexpr int POFF = 32768;
  const int t    = threadIdx.x;
  const int lane = t & 63;
  const int w    = t >> 6;          // 0..7, owns q-rows w*16..w*16+15
  const int l15  = lane & 15;
  const int lg   = lane >> 4;
  const int lq8  = lg * 8;
  const int lq4  = lg * 4;
  const int flat = blockIdx.x;
  const int bh   = flat & 63;
  const int qb   = flat >> 6;
  const int h    = bh & 15;
  const int b    = bh >> 4;
  const int q0   = qb * 128;
  const int hoff = h * kHD;
  constexpr int NT = kLK / 64;   // 32 kc-tiles

  // Q fragment: q-row = q0 + w*16 + l15
  bf16x8 qf[2];
#pragma unroll
  for (int kh = 0; kh < 2; ++kh)
    qf[kh] = *(const bf16x8*)(Q + (size_t)(b*kLQ + q0 + w*16 + l15) * kH
                                + hoff + kh*32 + lq8);

  f32x4 acc[4] = {};
  float lsum = 0.f;

  // P swizzle: row-local XOR of bits 4-6 by ((5*row)&7); row&7 == l15&7.
  const int swz  = ((l15 * 5) & 7) << 4;
  const int colw = (lg * 8)  ^ swz;   // write column base (b64)
  const int colr = (lg * 16) ^ swz;   // read column base (b128)
  char* const prow = lds + POFF + (w*16 + l15) * 128;

  // per-thread staging addresses (2 g2l per kc-tile; 512 threads stage 16KB)
  const unsigned short* gsrc[2];
  int gstep[2];
  char* ldst[2];
#pragma unroll
  for (int i = 0; i < 2; ++i) {
    const int g = w * 2 + i;
    if (g < 8) {
      gsrc[i]  = K + (size_t)(b*kLK + (g >> 1)*16 + l15) * kH + hoff + (g & 1)*32 + lq8;
      gstep[i] = 64 * kH;                       // advance 64 kc rows
    } else {
      const int gg = g - 8;
      gsrc[i]  = Vt + (size_t)(b*kH + hoff + (gg >> 1)*16 + l15) * kLK + (gg & 1)*32 + lq8;
      gstep[i] = 64;                            // advance 64 kc cols
    }
    ldst[i] = lds + g * 1024 + lane * 16;       // g>=8 lands at 8192+gg*1024
  }

  // prologue: tile 0 -> slot 0
  g2l16(gsrc[0], ldst[0]);
  g2l16(gsrc[1], ldst[1]);

  for (int kt = 0; kt < NT; ++kt) {
    // all outstanding loads are the current tile's (1-deep); drain + barrier
    asm volatile("s_waitcnt vmcnt(0)\n\ts_barrier" ::: "memory");
    char* buf = lds + (kt & 1) * 16384;
    if (kt + 1 < NT) {
      const int ns = (kt + 1) & 1;
      g2l16(gsrc[0] + (size_t)(kt + 1) * gstep[0], ldst[0] + ns * 16384);
      g2l16(gsrc[1] + (size_t)(kt + 1) * gstep[1], ldst[1] + ns * 16384);
    }

    // S^T = K Q^T : lane holds S[kc = kcf*16+lq4+r][q = w*16+l15]
    f32x4 s[4];
#pragma unroll
    for (int kcf = 0; kcf < 4; ++kcf) {
      const bf16x8 kf0 = *(const bf16x8*)(buf + (kcf*2 + 0) * 1024 + lane * 16);
      const bf16x8 kf1 = *(const bf16x8*)(buf + (kcf*2 + 1) * 1024 + lane * 16);
      f32x4 z = {};
      z = __builtin_amdgcn_mfma_f32_16x16x32_bf16(kf0, qf[0], z, 0, 0, 0);
      z = __builtin_amdgcn_mfma_f32_16x16x32_bf16(kf1, qf[1], z, 0, 0, 0);
      s[kcf] = z;
    }

    // P = exp2(s) (Q pre-scaled); pack 4 kc -> one b64 store per kcf.
#pragma unroll
    for (int kcf = 0; kcf < 4; ++kcf) {
      const float p0 = __builtin_amdgcn_exp2f(s[kcf][0]);
      const float p1 = __builtin_amdgcn_exp2f(s[kcf][1]);
      const float p2 = __builtin_amdgcn_exp2f(s[kcf][2]);
      const float p3 = __builtin_amdgcn_exp2f(s[kcf][3]);
      lsum += (p0 + p1) + (p2 + p3);
      u32x2 pw;
      pw.x = __builtin_amdgcn_perm(__float_as_uint(p1), __float_as_uint(p0), 0x07060302u);
      pw.y = __builtin_amdgcn_perm(__float_as_uint(p3), __float_as_uint(p2), 0x07060302u);
      *(u32x2*)(prow + (colw ^ (kcf * 32))) = pw;
    }

    // O += V^T P^T (swapped): acc[vd] reg r spans d = vd*16+lq4+r, l15 spans q.
    // P rows per-wave-private; no barrier needed.
    bf16x8 pf[2];
#pragma unroll
    for (int kq = 0; kq < 2; ++kq)
      pf[kq] = *(const bf16x8*)(prow + (colr ^ (kq * 64)));
#pragma unroll
    for (int vd = 0; vd < 4; ++vd) {
      const bf16x8 vf0 = *(const bf16x8*)(buf + 8192 + (vd*2 + 0) * 1024 + lane * 16);
      const bf16x8 vf1 = *(const bf16x8*)(buf + 8192 + (vd*2 + 1) * 1024 + lane * 16);
      acc[vd] = __builtin_amdgcn_mfma_f32_16x16x32_bf16(vf0, pf[0], acc[vd], 0, 0, 0);
      acc[vd] = __builtin_amdgcn_mfma_f32_16x16x32_bf16(vf1, pf[1], acc[vd], 0, 0, 0);
    }
  }

  // row sum: lane holds partial for q-row (w*16+l15) over its kc slice;
  // reduce across the 4 lane-groups. Lane-local to acc rows (q at l15).
  float v = lsum;
  v += __shfl_xor(v, 16);
  v += __shfl_xor(v, 32);
  const float rinv = 1.f / v;
#pragma unroll
  for (int vd = 0; vd < 4; ++vd) {
    ushort4 o;
    o.x = f2bf(acc[vd][0] * rinv);
    o.y = f2bf(acc[vd][1] * rinv);
    o.z = f2bf(acc[vd][2] * rinv);
    o.w = f2bf(acc[vd][3] * rinv);
    *(ushort4*)(O + (size_t)(b*kLQ + q0 + w*16 + l15) * kH
                  + hoff + vd*16 + lq4) = o;
  }
}

extern "C" void kernel_launch(void* const* d_in, const int* in_sizes, int n_in,
                              void* d_out, int out_size, void* d_ws, size_t ws_size,
                              hipStream_t stream) {
  (void)in_sizes; (void)n_in; (void)out_size; (void)ws_size;
  const float* query = (const float*)d_in[0];
  const float* key   = (const float*)d_in[1];
  const float* value = (const float*)d_in[2];
  const float* Wq = (const float*)d_in[3];
  const float* bq = (const float*)d_in[4];
  const float* Wk = (const float*)d_in[5];
  const float* bk = (const float*)d_in[6];
  const float* Wv = (const float*)d_in[7];
  const float* bv = (const float*)d_in[8];
  const float* Wo = (const float*)d_in[9];
  const float* bo = (const float*)d_in[10];
  float* out = (float*)d_out;

  unsigned short* ws  = (unsigned short*)d_ws;
  unsigned short* WqT = ws;                  // 1024*768
  unsigned short* WkT = WqT + 786432;        // 1024*512
  unsigned short* WvT = WkT + 524288;
  unsigned short* WoT = WvT + 524288;        // 1024*1024
  unsigned short* Qb  = WoT + 1048576;       // 4096*1024
  unsigned short* Kb  = Qb  + 4194304;       // 8192*1024
  unsigned short* Vtw = Kb  + 8388608;       // 4096*2048 (transposed V)
  unsigned short* Ab  = Vtw + 8388608;       // 4096*1024

  prep_kernel<<<704, 256, 0, stream>>>(Wq, Wk, Wv, Wo, WqT, WkT, WvT, WoT);
  qkv_gemm_kernel<<<1280, 256, 0, stream>>>(query, WqT, bq, Qb,
                                            key, WkT, bk, Kb,
                                            value, WvT, bv, Vtw);
  attn_mfma_kernel<<<512, 512, 0, stream>>>(Qb, Kb, Vtw, Ab);
  out_gemm_kernel<<<256, 256, 0, stream>>>(Ab, WoT, bo, out);
}

// Round 12
// 225.317 us; speedup vs baseline: 1.2094x; 1.2094x over previous
//
#include <hip/hip_runtime.h>
#include <math.h>

using bf16x8 = __attribute__((ext_vector_type(8))) short;
using f32x4  = __attribute__((ext_vector_type(4))) float;
using u32x2  = __attribute__((ext_vector_type(2))) unsigned int;

namespace {
constexpr int kB  = 4;
constexpr int kLQ = 1024;
constexpr int kLK = 2048;
constexpr int kH  = 1024;
constexpr int kHD = 64;
}

__device__ __forceinline__ unsigned short f2bf(float x) {
  union { float f; unsigned int u; } v; v.f = x;
  unsigned int r = v.u + 0x7fffu + ((v.u >> 16) & 1u);   // RNE
  return (unsigned short)(r >> 16);
}

// async global->LDS 16B copy
typedef const __attribute__((address_space(1))) unsigned int guint_t;
typedef __attribute__((address_space(3))) unsigned int luint_t;
__device__ __forceinline__ void g2l16(const void* g, void* l) {
  __builtin_amdgcn_global_load_lds(
      (guint_t*)g,
      (luint_t*)(unsigned int)(unsigned long long)l,
      16, 0, 0);
}

// --------- fused prep: fp32->bf16 casts (q,k,v) + 4 weight transposes --------
// (Standalone cast pass is deliberate: it reads each fp32 element ONCE.
// R11's fused-cast variant re-read fp32 A per column-block -> FETCH 93->183MB,
// qkv 58->153us. Do not re-fuse.)
__global__ __launch_bounds__(256) void prep_kernel(
    const float* __restrict__ q, const float* __restrict__ k,
    const float* __restrict__ v, const float* __restrict__ Wq,
    const float* __restrict__ Wk, const float* __restrict__ Wv,
    const float* __restrict__ Wo, unsigned short* __restrict__ qo,
    unsigned short* __restrict__ ko, unsigned short* __restrict__ vo,
    unsigned short* __restrict__ WqT, unsigned short* __restrict__ WkT,
    unsigned short* __restrict__ WvT, unsigned short* __restrict__ WoT)
{
  __shared__ float tile[64][65];
  const int t = threadIdx.x;
  if (blockIdx.x < 5632) {
    int c = blockIdx.x * 256 + t;
    const float* src; unsigned short* dst;
    if (c < 393216)      { src = q; dst = qo; }
    else if (c < 917504) { src = k; dst = ko; c -= 393216; }
    else                 { src = v; dst = vo; c -= 917504; }
    const int i = c * 8;
    const float4 a = *(const float4*)(src + i);
    const float4 b = *(const float4*)(src + i + 4);
    uint4 o;
    o.x = (unsigned int)f2bf(a.x) | ((unsigned int)f2bf(a.y) << 16);
    o.y = (unsigned int)f2bf(a.z) | ((unsigned int)f2bf(a.w) << 16);
    o.z = (unsigned int)f2bf(b.x) | ((unsigned int)f2bf(b.y) << 16);
    o.w = (unsigned int)f2bf(b.z) | ((unsigned int)f2bf(b.w) << 16);
    *(uint4*)(dst + i) = o;
    return;
  }
  int id = blockIdx.x - 5632;
  const float* W; unsigned short* Wt; int Kd;
  if (id < 192)      { W = Wq; Wt = WqT; Kd = 768; }
  else if (id < 320) { W = Wk; Wt = WkT; Kd = 512;  id -= 192; }
  else if (id < 448) { W = Wv; Wt = WvT; Kd = 512;  id -= 320; }
  else               { W = Wo; Wt = WoT; Kd = 1024; id -= 448; }
  const int Nd = 1024;
  const int n0 = (id & 15) * 64;
  const int k0 = (id >> 4) * 64;
  const int rr = t >> 4;
  const int c4 = t & 15;
#pragma unroll
  for (int i = 0; i < 4; ++i) {
    const int row = i * 16 + rr;
    const float4 vv = *(const float4*)(W + (size_t)(k0 + row) * Nd + n0 + c4 * 4);
    tile[row][c4*4+0] = vv.x; tile[row][c4*4+1] = vv.y;
    tile[row][c4*4+2] = vv.z; tile[row][c4*4+3] = vv.w;
  }
  __syncthreads();
#pragma unroll
  for (int i = 0; i < 4; ++i) {
    const int n = i * 16 + rr;
    ushort4 o;
    o.x = f2bf(tile[c4*4+0][n]); o.y = f2bf(tile[c4*4+1][n]);
    o.z = f2bf(tile[c4*4+2][n]); o.w = f2bf(tile[c4*4+3][n]);
    *(ushort4*)(Wt + (size_t)(n0 + n) * Kd + k0 + c4 * 4) = o;
  }
}

// ---- GEMM body: 128x128 tile, BK=32, TRIPLE-buffered counted-vmcnt pipeline -
// (R9-proven local optimum: 58.4us qkv. Falsified alternatives: 128x256
// 8-wave (R2), XCD swizzle (R3), B-direct-global (R8), 128x256 4-wave (R10),
// fused fp32 cast (R11). Do not touch the inner loop.)
// Raw `s_waitcnt vmcnt(4); s_barrier` waits only the CURRENT tile's 4 g2l per
// thread, leaving the next tile's 4 in flight across the barrier (T4).
// Modes 0/1 SWAPPED mfma(B,A): acc reg spans 4 consecutive output cols ->
// float4/ushort4 C-stores. mode 2 unswapped (V-transpose epilogue).
__device__ __forceinline__ void gemm_body(
    const unsigned short* __restrict__ A, const unsigned short* __restrict__ Bt,
    const float* __restrict__ bias, void* __restrict__ Cout,
    int N, int K, int bx, int by, int mode, float scale, char* lds)
{
  const int t    = threadIdx.x;
  const int lane = t & 63;
  const int w    = t >> 6;
  const int l15  = lane & 15;
  const int lq8  = (lane >> 4) * 8;
  const int lq4  = (lane >> 4) * 4;
  const int r0   = by * 128;
  const int c0   = bx * 128;
  const int wm   = w >> 1, wn = w & 1;

  f32x4 acc[4][4] = {};

  // per-thread staging addresses (4 g2l per K-tile)
  const unsigned short* gsrc[4];
  char* ldst[4];
#pragma unroll
  for (int i = 0; i < 4; ++i) {
    const int g = w * 4 + i;
    const unsigned short* src = (g < 8) ? A : Bt;
    const int rbase = (g < 8) ? (r0 + g * 16) : (c0 + (g - 8) * 16);
    gsrc[i] = src + (size_t)(rbase + l15) * K + lq8;
    ldst[i] = lds + g * 1024 + lane * 16;
  }

  // prologue: tile 0 -> slot 0, tile 1 -> slot 1
#pragma unroll
  for (int i = 0; i < 4; ++i) g2l16(gsrc[i], ldst[i]);
#pragma unroll
  for (int i = 0; i < 4; ++i) g2l16(gsrc[i] + 32, ldst[i] + 16384);

  int slot = 0;
  for (int k0 = 0; k0 < K; k0 += 32) {
    // wait for current tile only; keep next tile's loads in flight
    if (k0 + 32 < K) {
      asm volatile("s_waitcnt vmcnt(4)\n\ts_barrier" ::: "memory");
    } else {
      asm volatile("s_waitcnt vmcnt(0)\n\ts_barrier" ::: "memory");
    }
    char* buf = lds + slot * 16384;
    if (k0 + 64 < K) {
      int ns = slot + 2; if (ns >= 3) ns -= 3;   // slot of tile t+2
#pragma unroll
      for (int i = 0; i < 4; ++i)
        g2l16(gsrc[i] + k0 + 64, ldst[i] + ns * 16384);
    }
    bf16x8 af[4], bfr[4];
#pragma unroll
    for (int i = 0; i < 4; ++i) af[i]  = *(const bf16x8*)(buf + (wm*4 + i) * 1024 + lane * 16);
#pragma unroll
    for (int j = 0; j < 4; ++j) bfr[j] = *(const bf16x8*)(buf + 8192 + (wn*4 + j) * 1024 + lane * 16);
#pragma unroll
    for (int i = 0; i < 4; ++i)
#pragma unroll
      for (int j = 0; j < 4; ++j)
        acc[i][j] = (mode == 2)
          ? __builtin_amdgcn_mfma_f32_16x16x32_bf16(af[i], bfr[j], acc[i][j], 0, 0, 0)
          : __builtin_amdgcn_mfma_f32_16x16x32_bf16(bfr[j], af[i], acc[i][j], 0, 0, 0);
    slot = (slot == 2) ? 0 : slot + 1;
  }

  if (mode == 2) {
    // unswapped layout: reg spans rows (lq4+r), l15 spans cols
#pragma unroll
    for (int j = 0; j < 4; ++j) {
      const int col = c0 + wn * 64 + j * 16 + l15;
      const float bcol = bias[col];
#pragma unroll
      for (int i = 0; i < 4; ++i) {
        const int row = r0 + wm * 64 + i * 16 + lq4;
        unsigned short* out = (unsigned short*)Cout;
        const int bb = row >> 11;            // kLK = 2048
        const int lk = row & 2047;
        ushort4 o;
        o.x = f2bf(acc[i][j][0] + bcol); o.y = f2bf(acc[i][j][1] + bcol);
        o.z = f2bf(acc[i][j][2] + bcol); o.w = f2bf(acc[i][j][3] + bcol);
        *(ushort4*)(out + (size_t)(bb * kH + col) * kLK + lk) = o;
      }
    }
  } else {
    // swapped layout: l15 spans rows, reg spans 4 consecutive cols
#pragma unroll
    for (int i = 0; i < 4; ++i) {
      const int row = r0 + wm * 64 + i * 16 + l15;
#pragma unroll
      for (int j = 0; j < 4; ++j) {
        const int ncol = c0 + wn * 64 + j * 16 + lq4;
        const float4 b4 = *(const float4*)(bias + ncol);
        if (mode == 0) {
          float4 o;
          o.x = acc[i][j][0] + b4.x; o.y = acc[i][j][1] + b4.y;
          o.z = acc[i][j][2] + b4.z; o.w = acc[i][j][3] + b4.w;
          *(float4*)((float*)Cout + (size_t)row * N + ncol) = o;
        } else {
          ushort4 o;
          o.x = f2bf((acc[i][j][0] + b4.x) * scale);
          o.y = f2bf((acc[i][j][1] + b4.y) * scale);
          o.z = f2bf((acc[i][j][2] + b4.z) * scale);
          o.w = f2bf((acc[i][j][3] + b4.w) * scale);
          *(ushort4*)((unsigned short*)Cout + (size_t)row * N + ncol) = o;
        }
      }
    }
  }
}

// fused Q/K/V projections: blocks 0..255 Q | 256..767 K | 768..1279 V.
// UNSWIZZLED (R3 A/B: default bx=id&7 round-robin already pins one B-panel
// per XCD L2; swizzle regressed 62->80us). Q pre-scaled by log2(e)/sqrt(HD).
__global__ __launch_bounds__(256) void qkv_gemm_kernel(
    const unsigned short* __restrict__ qA, const unsigned short* __restrict__ WqT,
    const float* __restrict__ bq, unsigned short* __restrict__ Qb,
    const unsigned short* __restrict__ kA, const unsigned short* __restrict__ WkT,
    const float* __restrict__ bk, unsigned short* __restrict__ Kb,
    const unsigned short* __restrict__ vA, const unsigned short* __restrict__ WvT,
    const float* __restrict__ bv, unsigned short* __restrict__ Vtw)
{
  __shared__ __align__(16) char lds[49152];
  int id = blockIdx.x;
  if (id < 256) {
    gemm_body(qA, WqT, bq, Qb, 1024, 768, id & 7, id >> 3, 1,
              0.18033688011112042f, lds);   // log2(e)/8
  } else if (id < 768) {
    id -= 256;
    gemm_body(kA, WkT, bk, Kb, 1024, 512, id & 7, id >> 3, 1, 1.f, lds);
  } else {
    id -= 768;
    gemm_body(vA, WvT, bv, Vtw, 1024, 512, id & 7, id >> 3, 2, 1.f, lds);
  }
}

// out projection: fp32 out, 256 blocks of 128x128, 512 threads / 8 waves
// (each wave a 32x64 subtile; 2 g2l/thread, counted vmcnt(2)).
__global__ __launch_bounds__(512) void out_gemm_kernel(
    const unsigned short* __restrict__ A, const unsigned short* __restrict__ Bt,
    const float* __restrict__ bias, float* __restrict__ C)
{
  __shared__ __align__(16) char lds[49152];
  const int id   = blockIdx.x;
  const int t    = threadIdx.x;
  const int lane = t & 63;
  const int w    = t >> 6;          // 0..7
  const int l15  = lane & 15;
  const int lq8  = (lane >> 4) * 8;
  const int lq4  = (lane >> 4) * 4;
  const int r0   = (id >> 3) * 128;
  const int c0   = (id & 7) * 128;
  const int wm   = w >> 1;          // 0..3: 32-row subtile
  const int wn   = w & 1;           // 0..1: 64-col subtile
  constexpr int K = 1024, N = 1024;

  f32x4 acc[2][4] = {};

  const unsigned short* gsrc[2];
  char* ldst[2];
#pragma unroll
  for (int i = 0; i < 2; ++i) {
    const int g = w * 2 + i;
    const unsigned short* src = (g < 8) ? A : Bt;
    const int rbase = (g < 8) ? (r0 + g * 16) : (c0 + (g - 8) * 16);
    gsrc[i] = src + (size_t)(rbase + l15) * K + lq8;
    ldst[i] = lds + g * 1024 + lane * 16;
  }

  g2l16(gsrc[0], ldst[0]);
  g2l16(gsrc[1], ldst[1]);
  g2l16(gsrc[0] + 32, ldst[0] + 16384);
  g2l16(gsrc[1] + 32, ldst[1] + 16384);

  int slot = 0;
  for (int k0 = 0; k0 < K; k0 += 32) {
    if (k0 + 32 < K) {
      asm volatile("s_waitcnt vmcnt(2)\n\ts_barrier" ::: "memory");
    } else {
      asm volatile("s_waitcnt vmcnt(0)\n\ts_barrier" ::: "memory");
    }
    char* buf = lds + slot * 16384;
    if (k0 + 64 < K) {
      int ns = slot + 2; if (ns >= 3) ns -= 3;
      g2l16(gsrc[0] + k0 + 64, ldst[0] + ns * 16384);
      g2l16(gsrc[1] + k0 + 64, ldst[1] + ns * 16384);
    }
    bf16x8 af[2], bfr[4];
#pragma unroll
    for (int i = 0; i < 2; ++i) af[i]  = *(const bf16x8*)(buf + (wm*2 + i) * 1024 + lane * 16);
#pragma unroll
    for (int j = 0; j < 4; ++j) bfr[j] = *(const bf16x8*)(buf + 8192 + (wn*4 + j) * 1024 + lane * 16);
#pragma unroll
    for (int i = 0; i < 2; ++i)
#pragma unroll
      for (int j = 0; j < 4; ++j)
        acc[i][j] = __builtin_amdgcn_mfma_f32_16x16x32_bf16(bfr[j], af[i], acc[i][j], 0, 0, 0);
    slot = (slot == 2) ? 0 : slot + 1;
  }

  // swapped epilogue: l15 spans rows, reg spans 4 consecutive cols
#pragma unroll
  for (int i = 0; i < 2; ++i) {
    const int row = r0 + wm * 32 + i * 16 + l15;
#pragma unroll
    for (int j = 0; j < 4; ++j) {
      const int ncol = c0 + wn * 64 + j * 16 + lq4;
      const float4 b4 = *(const float4*)(bias + ncol);
      float4 o;
      o.x = acc[i][j][0] + b4.x; o.y = acc[i][j][1] + b4.y;
      o.z = acc[i][j][2] + b4.z; o.w = acc[i][j][3] + b4.w;
      *(float4*)(C + (size_t)row * N + ncol) = o;
    }
  }
}

// --------------------- MFMA flash attention (bf16, fp32 acc) -----------------
// Q [B*LQ, H] (pre-scaled by log2e/8), K [B*LK, H], Vt [B*H, LK], O [B*LQ, H].
// 8 waves x 16 q-rows (512 threads), kc-tile = 64, DOUBLE-buffered K/V;
// 48KB LDS -> 2 blocks/CU x 8 waves = 16 waves/CU: one wave's quarter-rate
// v_exp_f32 chain overlaps another's MFMA.
// QK^T SWAPPED (mfma(K,Q) = S^T); P 128 rows x 128B XOR-swizzled
// (byte ^= ((5*row)&7)<<4): conflict-free b128 reads, 2-way b64 writes (free).
// PV swapped (mfma(V,P)): lsum lane-local at q=l15, ushort4 O-stores.
// NEW (T5): s_setprio(1) around MFMA clusters — waves here have genuine
// mid-iteration role diversity (exp2/TRANS vs MFMA), the m191 prerequisite.
__global__ __launch_bounds__(512) void attn_mfma_kernel(
    const unsigned short* __restrict__ Q, const unsigned short* __restrict__ K,
    const unsigned short* __restrict__ Vt, unsigned short* __restrict__ O)
{
  // slot s at s*16384: K tile [0,8K) + V tile [8K,16K). P at 32768 (128 x 128B)
  __shared__ __align__(16) char lds[49152];
  constexpr int POFF = 32768;
  const int t    = threadIdx.x;
  const int lane = t & 63;
  const int w    = t >> 6;          // 0..7, owns q-rows w*16..w*16+15
  const int l15  = lane & 15;
  const int lg   = lane >> 4;
  const int lq8  = lg * 8;
  const int lq4  = lg * 4;
  const int flat = blockIdx.x;
  const int bh   = flat & 63;
  const int qb   = flat >> 6;
  const int h    = bh & 15;
  const int b    = bh >> 4;
  const int q0   = qb * 128;
  const int hoff = h * kHD;
  constexpr int NT = kLK / 64;   // 32 kc-tiles

  // Q fragment: q-row = q0 + w*16 + l15
  bf16x8 qf[2];
#pragma unroll
  for (int kh = 0; kh < 2; ++kh)
    qf[kh] = *(const bf16x8*)(Q + (size_t)(b*kLQ + q0 + w*16 + l15) * kH
                                + hoff + kh*32 + lq8);

  f32x4 acc[4] = {};
  float lsum = 0.f;

  // P swizzle: row-local XOR of bits 4-6 by ((5*row)&7); row&7 == l15&7.
  const int swz  = ((l15 * 5) & 7) << 4;
  const int colw = (lg * 8)  ^ swz;   // write column base (b64)
  const int colr = (lg * 16) ^ swz;   // read column base (b128)
  char* const prow = lds + POFF + (w*16 + l15) * 128;

  // per-thread staging addresses (2 g2l per kc-tile; 512 threads stage 16KB)
  const unsigned short* gsrc[2];
  int gstep[2];
  char* ldst[2];
#pragma unroll
  for (int i = 0; i < 2; ++i) {
    const int g = w * 2 + i;
    if (g < 8) {
      gsrc[i]  = K + (size_t)(b*kLK + (g >> 1)*16 + l15) * kH + hoff + (g & 1)*32 + lq8;
      gstep[i] = 64 * kH;                       // advance 64 kc rows
    } else {
      const int gg = g - 8;
      gsrc[i]  = Vt + (size_t)(b*kH + hoff + (gg >> 1)*16 + l15) * kLK + (gg & 1)*32 + lq8;
      gstep[i] = 64;                            // advance 64 kc cols
    }
    ldst[i] = lds + g * 1024 + lane * 16;       // g>=8 lands at 8192+gg*1024
  }

  // prologue: tile 0 -> slot 0
  g2l16(gsrc[0], ldst[0]);
  g2l16(gsrc[1], ldst[1]);

  for (int kt = 0; kt < NT; ++kt) {
    // all outstanding loads are the current tile's (1-deep); drain + barrier
    asm volatile("s_waitcnt vmcnt(0)\n\ts_barrier" ::: "memory");
    char* buf = lds + (kt & 1) * 16384;
    if (kt + 1 < NT) {
      const int ns = (kt + 1) & 1;
      g2l16(gsrc[0] + (size_t)(kt + 1) * gstep[0], ldst[0] + ns * 16384);
      g2l16(gsrc[1] + (size_t)(kt + 1) * gstep[1], ldst[1] + ns * 16384);
    }

    // S^T = K Q^T : lane holds S[kc = kcf*16+lq4+r][q = w*16+l15]
    f32x4 s[4];
    __builtin_amdgcn_s_setprio(1);
#pragma unroll
    for (int kcf = 0; kcf < 4; ++kcf) {
      const bf16x8 kf0 = *(const bf16x8*)(buf + (kcf*2 + 0) * 1024 + lane * 16);
      const bf16x8 kf1 = *(const bf16x8*)(buf + (kcf*2 + 1) * 1024 + lane * 16);
      f32x4 z = {};
      z = __builtin_amdgcn_mfma_f32_16x16x32_bf16(kf0, qf[0], z, 0, 0, 0);
      z = __builtin_amdgcn_mfma_f32_16x16x32_bf16(kf1, qf[1], z, 0, 0, 0);
      s[kcf] = z;
    }
    __builtin_amdgcn_s_setprio(0);

    // P = exp2(s) (Q pre-scaled); pack 4 kc -> one b64 store per kcf.
#pragma unroll
    for (int kcf = 0; kcf < 4; ++kcf) {
      const float p0 = __builtin_amdgcn_exp2f(s[kcf][0]);
      const float p1 = __builtin_amdgcn_exp2f(s[kcf][1]);
      const float p2 = __builtin_amdgcn_exp2f(s[kcf][2]);
      const float p3 = __builtin_amdgcn_exp2f(s[kcf][3]);
      lsum += (p0 + p1) + (p2 + p3);
      u32x2 pw;
      pw.x = __builtin_amdgcn_perm(__float_as_uint(p1), __float_as_uint(p0), 0x07060302u);
      pw.y = __builtin_amdgcn_perm(__float_as_uint(p3), __float_as_uint(p2), 0x07060302u);
      *(u32x2*)(prow + (colw ^ (kcf * 32))) = pw;
    }

    // O += V^T P^T (swapped): acc[vd] reg r spans d = vd*16+lq4+r, l15 spans q.
    // P rows per-wave-private; no barrier needed.
    bf16x8 pf[2];
#pragma unroll
    for (int kq = 0; kq < 2; ++kq)
      pf[kq] = *(const bf16x8*)(prow + (colr ^ (kq * 64)));
    __builtin_amdgcn_s_setprio(1);
#pragma unroll
    for (int vd = 0; vd < 4; ++vd) {
      const bf16x8 vf0 = *(const bf16x8*)(buf + 8192 + (vd*2 + 0) * 1024 + lane * 16);
      const bf16x8 vf1 = *(const bf16x8*)(buf + 8192 + (vd*2 + 1) * 1024 + lane * 16);
      acc[vd] = __builtin_amdgcn_mfma_f32_16x16x32_bf16(vf0, pf[0], acc[vd], 0, 0, 0);
      acc[vd] = __builtin_amdgcn_mfma_f32_16x16x32_bf16(vf1, pf[1], acc[vd], 0, 0, 0);
    }
    __builtin_amdgcn_s_setprio(0);
  }

  // row sum: lane holds partial for q-row (w*16+l15) over its kc slice;
  // reduce across the 4 lane-groups. Lane-local to acc rows (q at l15).
  float v = lsum;
  v += __shfl_xor(v, 16);
  v += __shfl_xor(v, 32);
  const float rinv = 1.f / v;
#pragma unroll
  for (int vd = 0; vd < 4; ++vd) {
    ushort4 o;
    o.x = f2bf(acc[vd][0] * rinv);
    o.y = f2bf(acc[vd][1] * rinv);
    o.z = f2bf(acc[vd][2] * rinv);
    o.w = f2bf(acc[vd][3] * rinv);
    *(ushort4*)(O + (size_t)(b*kLQ + q0 + w*16 + l15) * kH
                  + hoff + vd*16 + lq4) = o;
  }
}

extern "C" void kernel_launch(void* const* d_in, const int* in_sizes, int n_in,
                              void* d_out, int out_size, void* d_ws, size_t ws_size,
                              hipStream_t stream) {
  (void)in_sizes; (void)n_in; (void)out_size; (void)ws_size;
  const float* query = (const float*)d_in[0];
  const float* key   = (const float*)d_in[1];
  const float* value = (const float*)d_in[2];
  const float* Wq = (const float*)d_in[3];
  const float* bq = (const float*)d_in[4];
  const float* Wk = (const float*)d_in[5];
  const float* bk = (const float*)d_in[6];
  const float* Wv = (const float*)d_in[7];
  const float* bv = (const float*)d_in[8];
  const float* Wo = (const float*)d_in[9];
  const float* bo = (const float*)d_in[10];
  float* out = (float*)d_out;

  unsigned short* ws  = (unsigned short*)d_ws;
  unsigned short* qA  = ws;                  // 4*1024*768
  unsigned short* kA  = qA  + 3145728;       // 4*2048*512
  unsigned short* vA  = kA  + 4194304;
  unsigned short* WqT = vA  + 4194304;       // 1024*768
  unsigned short* WkT = WqT + 786432;        // 1024*512
  unsigned short* WvT = WkT + 524288;
  unsigned short* WoT = WvT + 524288;        // 1024*1024
  unsigned short* Qb  = WoT + 1048576;       // 4096*1024
  unsigned short* Kb  = Qb  + 4194304;       // 8192*1024
  unsigned short* Vtw = Kb  + 8388608;       // 4096*2048 (transposed V)
  unsigned short* Ab  = Vtw + 8388608;       // 4096*1024

  prep_kernel<<<6336, 256, 0, stream>>>(query, key, value, Wq, Wk, Wv, Wo,
                                        qA, kA, vA, WqT, WkT, WvT, WoT);
  qkv_gemm_kernel<<<1280, 256, 0, stream>>>(qA, WqT, bq, Qb,
                                            kA, WkT, bk, Kb,
                                            vA, WvT, bv, Vtw);
  attn_mfma_kernel<<<512, 512, 0, stream>>>(Qb, Kb, Vtw, Ab);
  out_gemm_kernel<<<256, 512, 0, stream>>>(Ab, WoT, bo, out);
}